// Round 1
// baseline (44.120 us; speedup 1.0000x reference)
//
#include <hip/hip_runtime.h>

// MPS batched contraction: out[b] = (e0^T * Π_i M_i(x[b,i]))[0]
// Per site GEMM (transposed): outT[d,b] = sum_k AmatT[d,k] * UT[k,b]
//   k = 2*l + p, U[b,k] = left[b,l]*x[b,p], Amat[k,d] = A[i,l,p,d]
// MFMA v_mfma_f32_32x32x16_f16, A-operand = AmatT (row=d=lane&31, k=(lane>>5)*8+e),
// B-operand = UT (col=b=lane&31, k=(lane>>5)*8+e), C/D: col=lane&31,
// row=(reg&3)+8*(reg>>2)+4*(lane>>5).  Chain property: B elem e of frag f
// equals Creg[4f+(e>>1)] * x[e&1]  -- no cross-lane movement between sites.

typedef _Float16 half8 __attribute__((ext_vector_type(8)));
typedef float floatx16 __attribute__((ext_vector_type(16)));

#define NSITES 64

// Pre-pack A (fp32 [64][32][2][32]) into fragment-ordered fp16:
// Af[((site*4+f)*64 + lane)*8 + e] = (f16) A[site][(f*16+h*8+e)>>1][e&1][lane&31], h=lane>>5
__global__ void mps_prep_afrag(const float* __restrict__ A, _Float16* __restrict__ Af) {
    int blk  = blockIdx.x;          // 0..255 = site*4 + f
    int site = blk >> 2;
    int f    = blk & 3;
    int lane = threadIdx.x;         // 0..63
    int h    = lane >> 5;
    int d    = lane & 31;
    half8 vals;
#pragma unroll
    for (int e = 0; e < 8; ++e) {
        int kg = f * 16 + h * 8 + e;
        int l  = kg >> 1;
        int p  = kg & 1;
        vals[e] = (_Float16)A[((site * 32 + l) * 2 + p) * 32 + d];
    }
    reinterpret_cast<half8*>(Af)[(site * 4 + f) * 64 + lane] = vals;
}

// One MFMA site-step. CURA = current site's A-frags, NXTA = buffer to prefetch
// the next site's A-frags into. S8 is a compile-time literal 0..7.
#define STEP(CURA, NXTA, S8)                                                     \
    {                                                                            \
        const int site_  = oct * 8 + (S8);                                       \
        const int nsite_ = (site_ + 1) & 63;                                     \
        _Pragma("unroll")                                                        \
        for (int f_ = 0; f_ < 4; ++f_)                                           \
            NXTA[f_] = ap[(nsite_ * 4 + f_) * 64 + lane];                        \
        const float x0_ = xs[2 * (S8)];                                          \
        const float x1_ = xs[2 * (S8) + 1];                                      \
        floatx16 nacc;                                                           \
        _Pragma("unroll")                                                        \
        for (int i_ = 0; i_ < 16; ++i_) nacc[i_] = 0.f;                          \
        _Pragma("unroll")                                                        \
        for (int f_ = 0; f_ < 4; ++f_) {                                         \
            half8 bf;                                                            \
            float c0 = acc[4 * f_ + 0];                                          \
            float c1 = acc[4 * f_ + 1];                                          \
            float c2 = acc[4 * f_ + 2];                                          \
            float c3 = acc[4 * f_ + 3];                                          \
            bf[0] = (_Float16)(c0 * x0_); bf[1] = (_Float16)(c0 * x1_);          \
            bf[2] = (_Float16)(c1 * x0_); bf[3] = (_Float16)(c1 * x1_);          \
            bf[4] = (_Float16)(c2 * x0_); bf[5] = (_Float16)(c2 * x1_);          \
            bf[6] = (_Float16)(c3 * x0_); bf[7] = (_Float16)(c3 * x1_);          \
            nacc = __builtin_amdgcn_mfma_f32_32x32x16_f16(CURA[f_], bf, nacc,    \
                                                          0, 0, 0);              \
        }                                                                        \
        acc = nacc;                                                              \
    }

__global__ __launch_bounds__(256, 2) void mps_main(const float* __restrict__ x,
                                                   const _Float16* __restrict__ Af,
                                                   float* __restrict__ out) {
    const int lane = threadIdx.x & 63;
    const int wid  = threadIdx.x >> 6;
    const int row0 = (blockIdx.x * 4 + wid) * 32;   // 32 batch rows per wave
    const int col  = lane & 31;
    const int b    = row0 + col;

    const float4* xp = reinterpret_cast<const float4*>(x + (size_t)b * (NSITES * 2));
    const half8*  ap = reinterpret_cast<const half8*>(Af);

    // accumulator holds left[b][l], l = (reg&3) + 8*(reg>>2) + 4*(lane>>5)
    floatx16 acc;
#pragma unroll
    for (int i = 0; i < 16; ++i) acc[i] = 0.f;
    if (lane < 32) acc[0] = 1.f;    // left0 = e0  (l==0 -> reg 0, lanes 0..31)

    // x octet buffer: 16 floats = 8 sites' (x0,x1) pairs, one 64B line per lane
    float xs[16], ys[16];
#define LOADX(dst, o)                                                            \
    {                                                                            \
        float4 t0 = xp[(o) * 4 + 0], t1 = xp[(o) * 4 + 1];                       \
        float4 t2 = xp[(o) * 4 + 2], t3 = xp[(o) * 4 + 3];                       \
        dst[0]  = t0.x; dst[1]  = t0.y; dst[2]  = t0.z; dst[3]  = t0.w;          \
        dst[4]  = t1.x; dst[5]  = t1.y; dst[6]  = t1.z; dst[7]  = t1.w;          \
        dst[8]  = t2.x; dst[9]  = t2.y; dst[10] = t2.z; dst[11] = t2.w;          \
        dst[12] = t3.x; dst[13] = t3.y; dst[14] = t3.z; dst[15] = t3.w;          \
    }

    LOADX(xs, 0);

    half8 A0[4], A1[4];
#pragma unroll
    for (int f = 0; f < 4; ++f) A0[f] = ap[f * 64 + lane];   // site 0 frags

    for (int oct = 0; oct < 8; ++oct) {
        const int noct = (oct + 1) & 7;        // wrap at end (harmless reload)
        LOADX(ys, noct);
        STEP(A0, A1, 0)
        STEP(A1, A0, 1)
        STEP(A0, A1, 2)
        STEP(A1, A0, 3)
        STEP(A0, A1, 4)
        STEP(A1, A0, 5)
        STEP(A0, A1, 6)
        STEP(A1, A0, 7)
#pragma unroll
        for (int i = 0; i < 16; ++i) xs[i] = ys[i];
    }

    // out[b] = left[b][0]: l==0 -> reg 0, lanes 0..31 (h==0)
    if (lane < 32) out[row0 + lane] = acc[0];
}

extern "C" void kernel_launch(void* const* d_in, const int* in_sizes, int n_in,
                              void* d_out, int out_size, void* d_ws, size_t ws_size,
                              hipStream_t stream) {
    const float* x = (const float*)d_in[0];   // [65536][64][2] f32
    const float* A = (const float*)d_in[1];   // [64][32][2][32] f32
    float* outp = (float*)d_out;              // [65536] f32
    _Float16* Af = (_Float16*)d_ws;           // 256 KB fragment-ordered fp16

    hipLaunchKernelGGL(mps_prep_afrag, dim3(NSITES * 4), dim3(64), 0, stream, A, Af);
    hipLaunchKernelGGL(mps_main, dim3(65536 / 128), dim3(256), 0, stream, x, Af, outp);
}

// Round 2
// 36.770 us; speedup vs baseline: 1.1999x; 1.1999x over previous
//
#include <hip/hip_runtime.h>

// MPS batched contraction: out[b] = (e0^T * Π_i M_i(x[b,i]))[0]
// Per site GEMM (transposed): outT[d,b] = sum_k AmatT[d,k] * UT[k,b]
//   k = 2*l + p, U[b,k] = left[b,l]*x[b,p], Amat[k,d] = A[i,l,p,d]
// MFMA v_mfma_f32_32x32x16_f16: A-op = AmatT (row=d=lane&31, k=(lane>>5)*8+e),
// B-op = UT (col=b=lane&31, k=(lane>>5)*8+e), C/D: col=lane&31,
// row=(reg&3)+8*(reg>>2)+4*(lane>>5).  Chain property: B elem e of frag f
// equals Creg[4f+(e>>1)] * x[e&1] in the SAME lane -- no cross-lane traffic.
//
// R2: 2 chains/wave (A-frags shared -> L1 traffic halved), 4-site-deep A
// prefetch (B0..B3 rotation, static s&3 indexing), acc<->nacc ping-pong via
// macro args (no per-site copies), loop-invariant zero vector as first
// MFMA's C operand (no per-site zero-init movs).

typedef _Float16 half8 __attribute__((ext_vector_type(8)));
typedef float floatx16 __attribute__((ext_vector_type(16)));

#define NSITES 64

// Pre-pack A (fp32 [64][32][2][32]) into fragment-ordered fp16:
// Af[((site*4+f)*64 + lane)*8 + e] = (f16) A[site][(f*16+h*8+e)>>1][e&1][lane&31]
__global__ void mps_prep_afrag(const float* __restrict__ A, _Float16* __restrict__ Af) {
    int blk  = blockIdx.x;          // 0..255 = site*4 + f
    int site = blk >> 2;
    int f    = blk & 3;
    int lane = threadIdx.x;         // 0..63
    int h    = lane >> 5;
    int d    = lane & 31;
    half8 vals;
#pragma unroll
    for (int e = 0; e < 8; ++e) {
        int kg = f * 16 + h * 8 + e;
        int l  = kg >> 1;
        int p  = kg & 1;
        vals[e] = (_Float16)A[((site * 32 + l) * 2 + p) * 32 + d];
    }
    reinterpret_cast<half8*>(Af)[(site * 4 + f) * 64 + lane] = vals;
}

// Build B-fragment F for one chain from its accumulator (f32 mul + RNE cvt,
// numerics identical to R1 which passed at absmax 0.0117).
#define FRAG(BF, ACC, F, X0, X1)                                              \
    {                                                                         \
        float c0_ = ACC[4 * (F) + 0], c1_ = ACC[4 * (F) + 1];                 \
        float c2_ = ACC[4 * (F) + 2], c3_ = ACC[4 * (F) + 3];                 \
        BF[0] = (_Float16)(c0_ * (X0)); BF[1] = (_Float16)(c0_ * (X1));       \
        BF[2] = (_Float16)(c1_ * (X0)); BF[3] = (_Float16)(c1_ * (X1));       \
        BF[4] = (_Float16)(c2_ * (X0)); BF[5] = (_Float16)(c2_ * (X1));       \
        BF[6] = (_Float16)(c3_ * (X0)); BF[7] = (_Float16)(c3_ * (X1));       \
    }

// One site-step for BOTH chains. CUR = this site's A-frag buffer (also the
// prefetch target for site S+4 -- same s&3 slot). XB*/XJ pick this site's
// (x0,x1) from the 4-site x quartet buffers.
#define STEP(S, CUR, AIN0, AOUT0, AIN1, AOUT1, XB0, XB1, XJ)                  \
    {                                                                         \
        const float x00_ = XB0[2 * (XJ)], x01_ = XB0[2 * (XJ) + 1];           \
        const float x10_ = XB1[2 * (XJ)], x11_ = XB1[2 * (XJ) + 1];           \
        half8 b0_, b1_, b2_, b3_, d0_, d1_, d2_, d3_;                         \
        FRAG(b0_, AIN0, 0, x00_, x01_);                                       \
        FRAG(d0_, AIN1, 0, x10_, x11_);                                       \
        FRAG(b1_, AIN0, 1, x00_, x01_);                                       \
        FRAG(d1_, AIN1, 1, x10_, x11_);                                       \
        FRAG(b2_, AIN0, 2, x00_, x01_);                                       \
        FRAG(d2_, AIN1, 2, x10_, x11_);                                       \
        FRAG(b3_, AIN0, 3, x00_, x01_);                                       \
        FRAG(d3_, AIN1, 3, x10_, x11_);                                       \
        AOUT0 = __builtin_amdgcn_mfma_f32_32x32x16_f16(CUR[0], b0_, zv, 0, 0, 0);     \
        AOUT1 = __builtin_amdgcn_mfma_f32_32x32x16_f16(CUR[0], d0_, zv, 0, 0, 0);     \
        AOUT0 = __builtin_amdgcn_mfma_f32_32x32x16_f16(CUR[1], b1_, AOUT0, 0, 0, 0);  \
        AOUT1 = __builtin_amdgcn_mfma_f32_32x32x16_f16(CUR[1], d1_, AOUT1, 0, 0, 0);  \
        AOUT0 = __builtin_amdgcn_mfma_f32_32x32x16_f16(CUR[2], b2_, AOUT0, 0, 0, 0);  \
        AOUT1 = __builtin_amdgcn_mfma_f32_32x32x16_f16(CUR[2], d2_, AOUT1, 0, 0, 0);  \
        AOUT0 = __builtin_amdgcn_mfma_f32_32x32x16_f16(CUR[3], b3_, AOUT0, 0, 0, 0);  \
        AOUT1 = __builtin_amdgcn_mfma_f32_32x32x16_f16(CUR[3], d3_, AOUT1, 0, 0, 0);  \
        const int ns_ = ((S) + 4) & 63;                                       \
        CUR[0] = ap[(ns_ * 4 + 0) * 64 + lane];                               \
        CUR[1] = ap[(ns_ * 4 + 1) * 64 + lane];                               \
        CUR[2] = ap[(ns_ * 4 + 2) * 64 + lane];                               \
        CUR[3] = ap[(ns_ * 4 + 3) * 64 + lane];                               \
    }

// Load one 4-site x quartet (8 floats = 2 float4) for one chain.
#define LOADQ(DST, XP, Q)                                                     \
    {                                                                         \
        float4 t0_ = XP[2 * (Q)], t1_ = XP[2 * (Q) + 1];                      \
        DST[0] = t0_.x; DST[1] = t0_.y; DST[2] = t0_.z; DST[3] = t0_.w;       \
        DST[4] = t1_.x; DST[5] = t1_.y; DST[6] = t1_.z; DST[7] = t1_.w;       \
    }

__global__ __launch_bounds__(256, 1) void mps_main(const float* __restrict__ x,
                                                   const _Float16* __restrict__ Af,
                                                   float* __restrict__ out) {
    const int lane = threadIdx.x & 63;
    const int wid  = threadIdx.x >> 6;
    const int row0 = (blockIdx.x * 4 + wid) * 64;   // 64 batch rows per wave
    const int col  = lane & 31;
    const int b0   = row0 + col;                    // chain 0 rows
    const int b1   = row0 + 32 + col;               // chain 1 rows

    const float4* xp0 = reinterpret_cast<const float4*>(x + (size_t)b0 * (NSITES * 2));
    const float4* xp1 = reinterpret_cast<const float4*>(x + (size_t)b1 * (NSITES * 2));
    const half8*  ap  = reinterpret_cast<const half8*>(Af);

    // Dedicated zero accumulator (loop-invariant, C operand of first MFMA)
    floatx16 zv;
#pragma unroll
    for (int i = 0; i < 16; ++i) zv[i] = 0.f;

    // acc holds left[b][l], l = (reg&3) + 8*(reg>>2) + 4*(lane>>5)
    floatx16 acc0, nacc0, acc1, nacc1;
#pragma unroll
    for (int i = 0; i < 16; ++i) { acc0[i] = 0.f; acc1[i] = 0.f; nacc0[i] = 0.f; nacc1[i] = 0.f; }
    if (lane < 32) { acc0[0] = 1.f; acc1[0] = 1.f; }   // left0 = e0

    // x quartet buffers (4 sites = 8 floats each), ping-pong xa/xb per chain
    float xa0[8], xb0[8], xa1[8], xb1[8];
    LOADQ(xa0, xp0, 0);
    LOADQ(xa1, xp1, 0);

    // A-frag buffers: site s uses B{s&3}; STEP refills its own slot with s+4
    half8 B0[4], B1[4], B2[4], B3[4];
#pragma unroll
    for (int f = 0; f < 4; ++f) {
        B0[f] = ap[(0 * 4 + f) * 64 + lane];
        B1[f] = ap[(1 * 4 + f) * 64 + lane];
        B2[f] = ap[(2 * 4 + f) * 64 + lane];
        B3[f] = ap[(3 * 4 + f) * 64 + lane];
    }

    for (int t = 0; t < 8; ++t) {                   // one octet (8 sites) per iter
        const int s0 = t * 8;
        const int q0 = t * 2;                        // quartet index of s0
        LOADQ(xb0, xp0, (q0 + 1) & 15);
        LOADQ(xb1, xp1, (q0 + 1) & 15);
        STEP(s0 + 0, B0, acc0, nacc0, acc1, nacc1, xa0, xa1, 0)
        STEP(s0 + 1, B1, nacc0, acc0, nacc1, acc1, xa0, xa1, 1)
        STEP(s0 + 2, B2, acc0, nacc0, acc1, nacc1, xa0, xa1, 2)
        STEP(s0 + 3, B3, nacc0, acc0, nacc1, acc1, xa0, xa1, 3)
        LOADQ(xa0, xp0, (q0 + 2) & 15);
        LOADQ(xa1, xp1, (q0 + 2) & 15);
        STEP(s0 + 4, B0, acc0, nacc0, acc1, nacc1, xb0, xb1, 0)
        STEP(s0 + 5, B1, nacc0, acc0, nacc1, acc1, xb0, xb1, 1)
        STEP(s0 + 6, B2, acc0, nacc0, acc1, nacc1, xb0, xb1, 2)
        STEP(s0 + 7, B3, nacc0, acc0, nacc1, acc1, xb0, xb1, 3)
    }

    // out[b] = left[b][0]: l==0 -> reg 0, lanes 0..31 (h==0)
    if (lane < 32) {
        out[row0 + lane]      = acc0[0];
        out[row0 + 32 + lane] = acc1[0];
    }
}

extern "C" void kernel_launch(void* const* d_in, const int* in_sizes, int n_in,
                              void* d_out, int out_size, void* d_ws, size_t ws_size,
                              hipStream_t stream) {
    const float* x = (const float*)d_in[0];   // [65536][64][2] f32
    const float* A = (const float*)d_in[1];   // [64][32][2][32] f32
    float* outp = (float*)d_out;              // [65536] f32
    _Float16* Af = (_Float16*)d_ws;           // 256 KB fragment-ordered fp16

    hipLaunchKernelGGL(mps_prep_afrag, dim3(NSITES * 4), dim3(64), 0, stream, A, Af);
    hipLaunchKernelGGL(mps_main, dim3(65536 / 256), dim3(256), 0, stream, x, Af, outp);
}